// Round 1
// baseline (554.969 us; speedup 1.0000x reference)
//
#include <hip/hip_runtime.h>
#include <hip/hip_bf16.h>
#include <cstdint>

// Problem constants (B=2, S=2048, DIM=1024, H=16, KVH=4, HD=64, WINDOW=256)
#define S_LEN 2048
#define QKV_COLS 1536   // 1024 q | 256 k | 256 v

typedef __bf16 bf16_t;
typedef bf16_t bf16x8 __attribute__((ext_vector_type(8)));
typedef bf16_t bf16x4 __attribute__((ext_vector_type(4)));
typedef float f32x4 __attribute__((ext_vector_type(4)));

typedef __attribute__((address_space(1))) void as1_void;
typedef __attribute__((address_space(3))) void as3_void;

__device__ __forceinline__ void async_load16(const void* g, void* lds) {
  __builtin_amdgcn_global_load_lds(
      (as1_void*)(uintptr_t)g,
      (as3_void*)(uint32_t)(uintptr_t)lds,
      16, 0, 0);
}

// ---------------- f32 -> bf16 conversion of x, Wq|Wk|Wv (concat), Wo ---------
// unit = 4 floats. regions (units): x 1048576 | Wq 262144 | Wk 65536 | Wv 65536 | Wo 262144
__global__ __launch_bounds__(256) void convert_all(
    const float4* __restrict__ x, const float4* __restrict__ wq,
    const float4* __restrict__ wk, const float4* __restrict__ wv,
    const float4* __restrict__ wo,
    bf16x4* __restrict__ xb, bf16x4* __restrict__ wqkvb, bf16x4* __restrict__ wob) {
  int u = blockIdx.x * 256 + threadIdx.x;
  const float4* src; bf16x4* dst; int off;
  if (u < 1048576)      { src = x;  dst = xb;            off = u; }
  else if (u < 1310720) { src = wq; dst = wqkvb;         off = u - 1048576; }
  else if (u < 1376256) { src = wk; dst = wqkvb + 262144; off = u - 1310720; }
  else if (u < 1441792) { src = wv; dst = wqkvb + 327680; off = u - 1376256; }
  else                  { src = wo; dst = wob;            off = u - 1441792; }
  float4 f = src[off];
  bf16x4 o;
  o[0] = (bf16_t)f.x; o[1] = (bf16_t)f.y; o[2] = (bf16_t)f.z; o[3] = (bf16_t)f.w;
  dst[off] = o;
}

// ---------------- bf16 MFMA GEMM: C[M,N] = A[M,K] * B[N,K]^T ----------------
// 128x128 tile, BK=32, 4 waves (each 64x64 = 4x4 MFMAs of 16x16x32).
template <bool OUT_BF16>
__global__ __launch_bounds__(256) void gemm_bt(
    const bf16_t* __restrict__ A, const bf16_t* __restrict__ B,
    void* __restrict__ Cv, int N, int K) {
  __shared__ bf16_t As[128 * 32];
  __shared__ bf16_t Bs[128 * 32];
  const int tid = threadIdx.x;
  const int lane = tid & 63;
  const int w = tid >> 6;
  const int wm = (w & 1) << 6, wn = (w >> 1) << 6;
  const int m0 = blockIdx.y << 7, n0 = blockIdx.x << 7;
  const int fidx = lane & 15, quad = lane >> 4;
  f32x4 acc[4][4] = {};
  const int c0 = tid, c1 = tid + 256;  // 16B chunks: row=c>>2, col8=(c&3)*8
  const bf16_t* Ag0 = A + (size_t)(m0 + (c0 >> 2)) * K + (c0 & 3) * 8;
  const bf16_t* Ag1 = A + (size_t)(m0 + (c1 >> 2)) * K + (c1 & 3) * 8;
  const bf16_t* Bg0 = B + (size_t)(n0 + (c0 >> 2)) * K + (c0 & 3) * 8;
  const bf16_t* Bg1 = B + (size_t)(n0 + (c1 >> 2)) * K + (c1 & 3) * 8;
  for (int kt = 0; kt < K; kt += 32) {
    __syncthreads();
    async_load16(Ag0 + kt, As + c0 * 8);
    async_load16(Ag1 + kt, As + c1 * 8);
    async_load16(Bg0 + kt, Bs + c0 * 8);
    async_load16(Bg1 + kt, Bs + c1 * 8);
    __syncthreads();
    bf16x8 af[4], bfr[4];
#pragma unroll
    for (int i = 0; i < 4; i++)
      af[i] = *(const bf16x8*)(As + (wm + i * 16 + fidx) * 32 + quad * 8);
#pragma unroll
    for (int i = 0; i < 4; i++)
      bfr[i] = *(const bf16x8*)(Bs + (wn + i * 16 + fidx) * 32 + quad * 8);
#pragma unroll
    for (int mi = 0; mi < 4; mi++)
#pragma unroll
      for (int ni = 0; ni < 4; ni++)
        acc[mi][ni] = __builtin_amdgcn_mfma_f32_16x16x32_bf16(
            af[mi], bfr[ni], acc[mi][ni], 0, 0, 0);
  }
  // C/D layout: col = lane&15, row = quad*4 + r
#pragma unroll
  for (int mi = 0; mi < 4; mi++)
#pragma unroll
    for (int ni = 0; ni < 4; ni++)
#pragma unroll
      for (int r = 0; r < 4; r++) {
        int gr = m0 + wm + mi * 16 + quad * 4 + r;
        int gc = n0 + wn + ni * 16 + fidx;
        float val = acc[mi][ni][r];
        if (OUT_BF16) ((bf16_t*)Cv)[(size_t)gr * N + gc] = (bf16_t)val;
        else          ((float*)Cv)[(size_t)gr * N + gc] = val;
      }
}

// ---------------- per-head RMSNorm + RoPE + q_gain (in place on qkv bf16) ---
// one wave per (token, slot); slots 0..15 = q heads, 16..19 = k heads
__global__ __launch_bounds__(256) void norm_rope(
    bf16_t* __restrict__ qkv, const float* __restrict__ q_gain) {
  int gw = (blockIdx.x * 256 + threadIdx.x) >> 6;
  int lane = threadIdx.x & 63;
  int t = gw / 20, slot = gw % 20;
  int s = t & (S_LEN - 1);
  float gain = 1.f; int col;
  if (slot < 16) { col = slot * 64; gain = q_gain[slot]; }
  else           { col = 1024 + (slot - 16) * 64; }
  bf16_t* p = qkv + (size_t)t * QKV_COLS + col;
  float v = (float)p[lane];
  float ss = v * v;
#pragma unroll
  for (int off = 32; off >= 1; off >>= 1) ss += __shfl_xor(ss, off);
  float vn = v * rsqrtf(ss * (1.f / 64.f) + 1e-6f);
  float partner = __shfl_xor(vn, 32);
  int f = lane & 31;
  float angle = (float)s * expf((float)f * -0.28782313662425575f);  // ln(1e4)/32
  float sn, cs;
  sincosf(angle, &sn, &cs);
  float outv = (lane < 32) ? (vn * cs + partner * sn) : (vn * cs - partner * sn);
  p[lane] = (bf16_t)(outv * gain);
}

// ---------------- windowed causal attention + pair mix ----------------------
// block = 4 waves: wave w -> (o = w&1 head-in-pair, qo = w>>1 query offset)
// grid: (S/2, H/2 pairs, B)
__global__ __launch_bounds__(256) void attn(
    const bf16_t* __restrict__ qkv, const float* __restrict__ pair_mix,
    bf16_t* __restrict__ yb) {
  __shared__ float qlds[4][64];
  __shared__ float plds[4][256];
  __shared__ float olds[4][64];
  const int tid = threadIdx.x, lane = tid & 63, w = tid >> 6;
  const int o = w & 1, qo = w >> 1;
  const int p = blockIdx.y, b = blockIdx.z;
  const int s = (blockIdx.x << 1) + qo;
  const int h = p * 2 + o, kvh = h >> 2;
  const size_t t = (size_t)b * S_LEN + s;

  float qv = (float)qkv[t * QKV_COLS + h * 64 + lane];
  qlds[w][lane] = qv;
  __syncthreads();

  const int kstart = max(0, s - 255);
  const int nk = s - kstart + 1;  // <= 256
  const bf16_t* kbase = qkv + ((size_t)b * S_LEN + kstart) * QKV_COLS + 1024 + kvh * 64;

  // phase 1: key-parallel scores (lane j handles keys j, j+64, j+128, j+192)
  float sc[4];
#pragma unroll
  for (int c = 0; c < 4; c++) {
    int kl = c * 64 + lane;
    if (kl < nk) {
      const bf16_t* krow = kbase + (size_t)kl * QKV_COLS;
      float acc = 0.f;
#pragma unroll
      for (int dd = 0; dd < 64; dd += 8) {
        bf16x8 k8 = *(const bf16x8*)(krow + dd);
#pragma unroll
        for (int j = 0; j < 8; j++) acc += qlds[w][dd + j] * (float)k8[j];
      }
      sc[c] = acc * 0.125f;  // 1/sqrt(64)
    } else {
      sc[c] = -INFINITY;
    }
  }
  float m = fmaxf(fmaxf(sc[0], sc[1]), fmaxf(sc[2], sc[3]));
#pragma unroll
  for (int off = 32; off >= 1; off >>= 1) m = fmaxf(m, __shfl_xor(m, off));
  float pr[4], sum = 0.f;
#pragma unroll
  for (int c = 0; c < 4; c++) {
    pr[c] = (c * 64 + lane < nk) ? expf(sc[c] - m) : 0.f;
    sum += pr[c];
  }
#pragma unroll
  for (int off = 32; off >= 1; off >>= 1) sum += __shfl_xor(sum, off);
  float inv = 1.f / sum;
#pragma unroll
  for (int c = 0; c < 4; c++) plds[w][c * 64 + lane] = pr[c] * inv;

  // phase 2: dim-parallel PV (lane = d)
  const bf16_t* vbase = qkv + ((size_t)b * S_LEN + kstart) * QKV_COLS + 1280 + kvh * 64 + lane;
  float acc = 0.f;
  int kl = 0;
  for (; kl + 4 <= nk; kl += 4) {
    float v0 = (float)vbase[(size_t)(kl + 0) * QKV_COLS];
    float v1 = (float)vbase[(size_t)(kl + 1) * QKV_COLS];
    float v2 = (float)vbase[(size_t)(kl + 2) * QKV_COLS];
    float v3 = (float)vbase[(size_t)(kl + 3) * QKV_COLS];
    acc += plds[w][kl] * v0 + plds[w][kl + 1] * v1 + plds[w][kl + 2] * v2 + plds[w][kl + 3] * v3;
  }
  for (; kl < nk; kl++) acc += plds[w][kl] * (float)vbase[(size_t)kl * QKV_COLS];
  olds[w][lane] = acc;
  __syncthreads();

  // pair mix: y'[h=2p+o] = pm[p][o][0]*y[2p] + pm[p][o][1]*y[2p+1]
  const int base = w & ~1;
  float pm0 = pair_mix[(p * 2 + o) * 2 + 0];
  float pm1 = pair_mix[(p * 2 + o) * 2 + 1];
  float mixed = pm0 * olds[base][lane] + pm1 * olds[base + 1][lane];
  yb[t * 1024 + h * 64 + lane] = (bf16_t)mixed;
}

extern "C" void kernel_launch(void* const* d_in, const int* in_sizes, int n_in,
                              void* d_out, int out_size, void* d_ws, size_t ws_size,
                              hipStream_t stream) {
  const float* x        = (const float*)d_in[0];
  const float* Wq       = (const float*)d_in[1];
  const float* Wk       = (const float*)d_in[2];
  const float* Wv       = (const float*)d_in[3];
  const float* Wo       = (const float*)d_in[4];
  const float* q_gain   = (const float*)d_in[5];
  const float* pair_mix = (const float*)d_in[6];
  float* out = (float*)d_out;

  bf16_t* ws    = (bf16_t*)d_ws;
  bf16_t* xb    = ws;                   // 4096*1024
  bf16_t* wqkvb = xb + 4096 * 1024;     // 1536*1024
  bf16_t* wob   = wqkvb + 1536 * 1024;  // 1024*1024
  bf16_t* qkvb  = wob + 1024 * 1024;    // 4096*1536
  bf16_t* yb    = qkvb + 4096 * 1536;   // 4096*1024  (total ~34.6 MB)

  convert_all<<<6656, 256, 0, stream>>>(
      (const float4*)x, (const float4*)Wq, (const float4*)Wk, (const float4*)Wv,
      (const float4*)Wo, (bf16x4*)xb, (bf16x4*)wqkvb, (bf16x4*)wob);
  gemm_bt<true><<<dim3(12, 32), 256, 0, stream>>>(xb, wqkvb, (void*)qkvb, 1536, 1024);
  norm_rope<<<20480, 256, 0, stream>>>(qkvb, q_gain);
  attn<<<dim3(1024, 8, 2), 256, 0, stream>>>(qkvb, pair_mix, yb);
  gemm_bt<false><<<dim3(8, 32), 256, 0, stream>>>(yb, wob, (void*)out, 1024, 1024);
}

// Round 2
// 197.871 us; speedup vs baseline: 2.8047x; 2.8047x over previous
//
#include <hip/hip_runtime.h>
#include <hip/hip_bf16.h>
#include <cstdint>

// Problem constants (B=2, S=2048, DIM=1024, H=16, KVH=4, HD=64, WINDOW=256)
#define S_LEN 2048
#define QKV_COLS 1536   // 1024 q | 256 k | 256 v

typedef __bf16 bf16_t;
typedef bf16_t bf16x8 __attribute__((ext_vector_type(8)));
typedef bf16_t bf16x4 __attribute__((ext_vector_type(4)));
typedef float f32x4 __attribute__((ext_vector_type(4)));

typedef __attribute__((address_space(1))) void as1_void;
typedef __attribute__((address_space(3))) void as3_void;

__device__ __forceinline__ void async_load16(const void* g, void* lds) {
  __builtin_amdgcn_global_load_lds(
      (as1_void*)(uintptr_t)g,
      (as3_void*)(uint32_t)(uintptr_t)lds,
      16, 0, 0);
}

// ---------------- f32 -> bf16 conversion of x, Wq|Wk|Wv (concat), Wo ---------
__global__ __launch_bounds__(256) void convert_all(
    const float4* __restrict__ x, const float4* __restrict__ wq,
    const float4* __restrict__ wk, const float4* __restrict__ wv,
    const float4* __restrict__ wo,
    bf16x4* __restrict__ xb, bf16x4* __restrict__ wqkvb, bf16x4* __restrict__ wob) {
  int u = blockIdx.x * 256 + threadIdx.x;
  const float4* src; bf16x4* dst; int off;
  if (u < 1048576)      { src = x;  dst = xb;            off = u; }
  else if (u < 1310720) { src = wq; dst = wqkvb;         off = u - 1048576; }
  else if (u < 1376256) { src = wk; dst = wqkvb + 262144; off = u - 1310720; }
  else if (u < 1441792) { src = wv; dst = wqkvb + 327680; off = u - 1376256; }
  else                  { src = wo; dst = wob;            off = u - 1441792; }
  float4 f = src[off];
  bf16x4 o;
  o[0] = (bf16_t)f.x; o[1] = (bf16_t)f.y; o[2] = (bf16_t)f.z; o[3] = (bf16_t)f.w;
  dst[off] = o;
}

// ---------------- bf16 MFMA GEMM: C[M,N] = A[M,K] * B[N,K]^T ----------------
template <bool OUT_BF16>
__global__ __launch_bounds__(256) void gemm_bt(
    const bf16_t* __restrict__ A, const bf16_t* __restrict__ B,
    void* __restrict__ Cv, int N, int K) {
  __shared__ bf16_t As[128 * 32];
  __shared__ bf16_t Bs[128 * 32];
  const int tid = threadIdx.x;
  const int lane = tid & 63;
  const int w = tid >> 6;
  const int wm = (w & 1) << 6, wn = (w >> 1) << 6;
  const int m0 = blockIdx.y << 7, n0 = blockIdx.x << 7;
  const int fidx = lane & 15, quad = lane >> 4;
  f32x4 acc[4][4] = {};
  const int c0 = tid, c1 = tid + 256;
  const bf16_t* Ag0 = A + (size_t)(m0 + (c0 >> 2)) * K + (c0 & 3) * 8;
  const bf16_t* Ag1 = A + (size_t)(m0 + (c1 >> 2)) * K + (c1 & 3) * 8;
  const bf16_t* Bg0 = B + (size_t)(n0 + (c0 >> 2)) * K + (c0 & 3) * 8;
  const bf16_t* Bg1 = B + (size_t)(n0 + (c1 >> 2)) * K + (c1 & 3) * 8;
  for (int kt = 0; kt < K; kt += 32) {
    __syncthreads();
    async_load16(Ag0 + kt, As + c0 * 8);
    async_load16(Ag1 + kt, As + c1 * 8);
    async_load16(Bg0 + kt, Bs + c0 * 8);
    async_load16(Bg1 + kt, Bs + c1 * 8);
    __syncthreads();
    bf16x8 af[4], bfr[4];
#pragma unroll
    for (int i = 0; i < 4; i++)
      af[i] = *(const bf16x8*)(As + (wm + i * 16 + fidx) * 32 + quad * 8);
#pragma unroll
    for (int i = 0; i < 4; i++)
      bfr[i] = *(const bf16x8*)(Bs + (wn + i * 16 + fidx) * 32 + quad * 8);
#pragma unroll
    for (int mi = 0; mi < 4; mi++)
#pragma unroll
      for (int ni = 0; ni < 4; ni++)
        acc[mi][ni] = __builtin_amdgcn_mfma_f32_16x16x32_bf16(
            af[mi], bfr[ni], acc[mi][ni], 0, 0, 0);
  }
#pragma unroll
  for (int mi = 0; mi < 4; mi++)
#pragma unroll
    for (int ni = 0; ni < 4; ni++)
#pragma unroll
      for (int r = 0; r < 4; r++) {
        int gr = m0 + wm + mi * 16 + quad * 4 + r;
        int gc = n0 + wn + ni * 16 + fidx;
        float val = acc[mi][ni][r];
        if (OUT_BF16) ((bf16_t*)Cv)[(size_t)gr * N + gc] = (bf16_t)val;
        else          ((float*)Cv)[(size_t)gr * N + gc] = val;
      }
}

// ---------------- per-head RMSNorm + RoPE + q_gain (in place on qkv bf16) ---
// one wave per (token, slot); slots 0..15 = q heads, 16..19 = k heads
// NOTE: softmax scale 1/sqrt(64)=0.125 folded into q gain (rotation commutes
// with scalar, so scaling before RoPE is equivalent).
__global__ __launch_bounds__(256) void norm_rope(
    bf16_t* __restrict__ qkv, const float* __restrict__ q_gain) {
  int gw = (blockIdx.x * 256 + threadIdx.x) >> 6;
  int lane = threadIdx.x & 63;
  int t = gw / 20, slot = gw % 20;
  int s = t & (S_LEN - 1);
  float gain = 1.f; int col;
  if (slot < 16) { col = slot * 64; gain = q_gain[slot] * 0.125f; }
  else           { col = 1024 + (slot - 16) * 64; }
  bf16_t* p = qkv + (size_t)t * QKV_COLS + col;
  float v = (float)p[lane];
  float ss = v * v;
#pragma unroll
  for (int off = 32; off >= 1; off >>= 1) ss += __shfl_xor(ss, off);
  float vn = v * rsqrtf(ss * (1.f / 64.f) + 1e-6f);
  float partner = __shfl_xor(vn, 32);
  int f = lane & 31;
  float angle = (float)s * expf((float)f * -0.28782313662425575f);  // ln(1e4)/32
  float sn, cs;
  sincosf(angle, &sn, &cs);
  float outv = (lane < 32) ? (vn * cs + partner * sn) : (vn * cs - partner * sn);
  p[lane] = (bf16_t)(outv * gain);
}

// ---------------- V transpose: vt[(b*4+g)*64 + d][s] = V[b][s][g][d] --------
// grid (S/64, KVH, B), 256 threads; 64x64 tile via LDS.
__global__ __launch_bounds__(256) void transpose_v(
    const bf16_t* __restrict__ qkv, bf16_t* __restrict__ vt) {
  __shared__ bf16_t tile[64][72];
  const int tid = threadIdx.x;
  const int s0 = blockIdx.x * 64, g = blockIdx.y, b = blockIdx.z;
  const int r = tid >> 2, cg = (tid & 3) * 16;
  const bf16_t* src = qkv + ((size_t)b * S_LEN + s0 + r) * QKV_COLS + 1280 + g * 64 + cg;
  bf16x8 a0 = *(const bf16x8*)src;
  bf16x8 a1 = *(const bf16x8*)(src + 8);
#pragma unroll
  for (int j = 0; j < 8; j++) { tile[r][cg + j] = a0[j]; tile[r][cg + 8 + j] = a1[j]; }
  __syncthreads();
  bf16x8 o0, o1;
#pragma unroll
  for (int j = 0; j < 8; j++) { o0[j] = tile[cg + j][r]; o1[j] = tile[cg + 8 + j][r]; }
  bf16_t* dst = vt + ((size_t)(b * 4 + g) * 64 + r) * S_LEN + s0 + cg;
  *(bf16x8*)dst = o0;
  *(bf16x8*)(dst + 8) = o1;
}

// ---------------- MFMA flash attention + pair mix ---------------------------
// block = (b, kvh group g, 16-query tile). 4 waves = 4 q heads of the group.
// Per wave: M-tile of 16 queries, iterate 32-key chunks with online softmax.
// MFMA 16x16x32: A/B frag = [idx=lane&15][k=quad*8+j]; C/D: col=lane&15,
// row=quad*4+r.
#define PSTRIDE 40  // P tile row stride (bf16) — 80B, keeps ds_read_b128 aligned
__global__ __launch_bounds__(256) void attn_mfma(
    const bf16_t* __restrict__ qkv, const bf16_t* __restrict__ vt,
    const float* __restrict__ pair_mix, bf16_t* __restrict__ yb) {
  __shared__ bf16_t plds[4][16 * PSTRIDE];
  __shared__ float olds[4][16][64];
  const int tid = threadIdx.x, lane = tid & 63, w = tid >> 6;
  const int col = lane & 15, quad = lane >> 4;
  const int q0 = blockIdx.x * 16, g = blockIdx.y, b = blockIdx.z;
  const int h = g * 4 + w;

  // Q fragments (scores scale pre-folded into q)
  const bf16_t* qbase = qkv + ((size_t)b * S_LEN + q0 + col) * QKV_COLS + h * 64 + quad * 8;
  bf16x8 qf0 = *(const bf16x8*)(qbase);
  bf16x8 qf1 = *(const bf16x8*)(qbase + 32);

  const bf16_t* kbase = qkv + (size_t)b * S_LEN * QKV_COLS + 1024 + g * 64 + quad * 8;
  const bf16_t* vbase = vt + ((size_t)(b * 4 + g) * 64 + col) * S_LEN + quad * 8;

  f32x4 o[4] = {};
  float m[4], l[4];
#pragma unroll
  for (int r = 0; r < 4; r++) { m[r] = -1e30f; l[r] = 0.f; }

  const int c_lo = max(0, (q0 - 255) >> 5);
  const int c_hi = (q0 + 15) >> 5;
  for (int c = c_lo; c <= c_hi; c++) {
    const int k0 = c * 32;
    // ---- scores: S[16q x 32k], 2 N-tiles x 2 Kdim-halves
    f32x4 s[2];
#pragma unroll
    for (int nt = 0; nt < 2; nt++) {
      const bf16_t* kp = kbase + (size_t)(k0 + nt * 16 + col) * QKV_COLS;
      bf16x8 kf0 = *(const bf16x8*)(kp);
      bf16x8 kf1 = *(const bf16x8*)(kp + 32);
      f32x4 acc = {};
      acc = __builtin_amdgcn_mfma_f32_16x16x32_bf16(qf0, kf0, acc, 0, 0, 0);
      acc = __builtin_amdgcn_mfma_f32_16x16x32_bf16(qf1, kf1, acc, 0, 0, 0);
      s[nt] = acc;
    }
    // ---- mask + chunk row-max (shfl over 16-lane col group: xor 1,2,4,8)
    float alpha[4];
#pragma unroll
    for (int r = 0; r < 4; r++) {
      int q = q0 + quad * 4 + r;
#pragma unroll
      for (int nt = 0; nt < 2; nt++) {
        int k = k0 + nt * 16 + col;
        bool valid = (k <= q) && (q - k < 256);
        s[nt][r] = valid ? s[nt][r] : -1e30f;
      }
      float v = fmaxf(s[0][r], s[1][r]);
#pragma unroll
      for (int off = 8; off >= 1; off >>= 1) v = fmaxf(v, __shfl_xor(v, off));
      float mn = fmaxf(m[r], v);
      alpha[r] = __expf(m[r] - mn);  // both -1e30 -> exp(0)=1 (l,o still 0: ok)
      m[r] = mn;
    }
    // ---- P = exp(s - m), write to LDS (bf16), row sums
    float psum[4] = {0.f, 0.f, 0.f, 0.f};
#pragma unroll
    for (int nt = 0; nt < 2; nt++) {
#pragma unroll
      for (int r = 0; r < 4; r++) {
        float sv = s[nt][r];
        float p = (sv > -1e29f) ? __expf(sv - m[r]) : 0.f;  // guard all-masked rows
        psum[r] += p;
        plds[w][(quad * 4 + r) * PSTRIDE + nt * 16 + col] = (bf16_t)p;
      }
    }
#pragma unroll
    for (int r = 0; r < 4; r++) {
      float v = psum[r];
#pragma unroll
      for (int off = 8; off >= 1; off >>= 1) v += __shfl_xor(v, off);
      l[r] = l[r] * alpha[r] + v;
#pragma unroll
      for (int nt2 = 0; nt2 < 4; nt2++) o[nt2][r] *= alpha[r];
    }
    // ---- P A-frag from LDS, PV MFMAs against transposed V
    asm volatile("s_waitcnt lgkmcnt(0)" ::: "memory");
    bf16x8 pf = *(const bf16x8*)(plds[w] + col * PSTRIDE + quad * 8);
#pragma unroll
    for (int nt2 = 0; nt2 < 4; nt2++) {
      bf16x8 vf = *(const bf16x8*)(vbase + (size_t)(nt2 * 16) * S_LEN + k0);
      o[nt2] = __builtin_amdgcn_mfma_f32_16x16x32_bf16(pf, vf, o[nt2], 0, 0, 0);
    }
  }
  // ---- normalize, stash per-head O in LDS
#pragma unroll
  for (int r = 0; r < 4; r++) {
    float il = 1.f / l[r];
#pragma unroll
    for (int nt2 = 0; nt2 < 4; nt2++)
      olds[w][quad * 4 + r][nt2 * 16 + col] = o[nt2][r] * il;
  }
  __syncthreads();
  // ---- pair mix + coalesced bf16x8 writes (4096 outputs/block)
#pragma unroll
  for (int i = 0; i < 2; i++) {
    int chunk = tid * 2 + i;      // 0..511
    int tok = chunk >> 5;         // 0..15
    int cg = chunk & 31;          // 8-elem col group within 256 cols
    int hh = cg >> 3;             // head within group
    int d0 = (cg & 7) * 8;
    int p_loc = hh >> 1, oo = hh & 1;
    int wb = p_loc * 2;
    int hp = g * 2 + p_loc;       // global pair index
    float pm0 = pair_mix[hp * 4 + oo * 2 + 0];
    float pm1 = pair_mix[hp * 4 + oo * 2 + 1];
    bf16x8 outv;
#pragma unroll
    for (int j = 0; j < 8; j++)
      outv[j] = (bf16_t)(pm0 * olds[wb][tok][d0 + j] + pm1 * olds[wb + 1][tok][d0 + j]);
    *(bf16x8*)(yb + ((size_t)b * S_LEN + q0 + tok) * 1024 + (g * 4 + hh) * 64 + d0) = outv;
  }
}

extern "C" void kernel_launch(void* const* d_in, const int* in_sizes, int n_in,
                              void* d_out, int out_size, void* d_ws, size_t ws_size,
                              hipStream_t stream) {
  const float* x        = (const float*)d_in[0];
  const float* Wq       = (const float*)d_in[1];
  const float* Wk       = (const float*)d_in[2];
  const float* Wv       = (const float*)d_in[3];
  const float* Wo       = (const float*)d_in[4];
  const float* q_gain   = (const float*)d_in[5];
  const float* pair_mix = (const float*)d_in[6];
  float* out = (float*)d_out;

  bf16_t* ws    = (bf16_t*)d_ws;
  bf16_t* xb    = ws;                   // 4096*1024 (dead after gemm1; vt aliases it)
  bf16_t* wqkvb = xb + 4096 * 1024;     // 1536*1024
  bf16_t* wob   = wqkvb + 1536 * 1024;  // 1024*1024
  bf16_t* qkvb  = wob + 1024 * 1024;    // 4096*1536
  bf16_t* yb    = qkvb + 4096 * 1536;   // 4096*1024  (total ~34.6 MB)
  bf16_t* vt    = xb;                   // 8*64*2048 = 1M bf16, aliases xb

  convert_all<<<6656, 256, 0, stream>>>(
      (const float4*)x, (const float4*)Wq, (const float4*)Wk, (const float4*)Wv,
      (const float4*)Wo, (bf16x4*)xb, (bf16x4*)wqkvb, (bf16x4*)wob);
  gemm_bt<true><<<dim3(12, 32), 256, 0, stream>>>(xb, wqkvb, (void*)qkvb, 1536, 1024);
  norm_rope<<<20480, 256, 0, stream>>>(qkvb, q_gain);
  transpose_v<<<dim3(32, 4, 2), 256, 0, stream>>>(qkvb, vt);
  attn_mfma<<<dim3(128, 4, 2), 256, 0, stream>>>(qkvb, vt, pair_mix, yb);
  gemm_bt<false><<<dim3(8, 32), 256, 0, stream>>>(yb, wob, (void*)out, 1024, 1024);
}

// Round 3
// 177.543 us; speedup vs baseline: 3.1258x; 1.1145x over previous
//
#include <hip/hip_runtime.h>
#include <hip/hip_bf16.h>
#include <cstdint>

// Problem constants (B=2, S=2048, DIM=1024, H=16, KVH=4, HD=64, WINDOW=256)
#define S_LEN 2048
#define QKV_COLS 1536   // 1024 q | 256 k | 256 v

typedef __bf16 bf16_t;
typedef bf16_t bf16x8 __attribute__((ext_vector_type(8)));
typedef bf16_t bf16x4 __attribute__((ext_vector_type(4)));
typedef float f32x4 __attribute__((ext_vector_type(4)));

typedef __attribute__((address_space(1))) void as1_void;
typedef __attribute__((address_space(3))) void as3_void;

__device__ __forceinline__ void async_load16(const void* g, void* lds) {
  __builtin_amdgcn_global_load_lds(
      (as1_void*)(uintptr_t)g,
      (as3_void*)(uint32_t)(uintptr_t)lds,
      16, 0, 0);
}

// ---------------- f32 -> bf16 conversion of x, Wq|Wk|Wv (concat), Wo ---------
__global__ __launch_bounds__(256) void convert_all(
    const float4* __restrict__ x, const float4* __restrict__ wq,
    const float4* __restrict__ wk, const float4* __restrict__ wv,
    const float4* __restrict__ wo,
    bf16x4* __restrict__ xb, bf16x4* __restrict__ wqkvb, bf16x4* __restrict__ wob) {
  int u = blockIdx.x * 256 + threadIdx.x;
  const float4* src; bf16x4* dst; int off;
  if (u < 1048576)      { src = x;  dst = xb;            off = u; }
  else if (u < 1310720) { src = wq; dst = wqkvb;         off = u - 1048576; }
  else if (u < 1376256) { src = wk; dst = wqkvb + 262144; off = u - 1310720; }
  else if (u < 1441792) { src = wv; dst = wqkvb + 327680; off = u - 1376256; }
  else                  { src = wo; dst = wob;            off = u - 1441792; }
  float4 f = src[off];
  bf16x4 o;
  o[0] = (bf16_t)f.x; o[1] = (bf16_t)f.y; o[2] = (bf16_t)f.z; o[3] = (bf16_t)f.w;
  dst[off] = o;
}

// ---------------- QKV GEMM + fused RMSNorm/RoPE/gain epilogue ---------------
// C[M,1536] = A[M,1024] * B[1536,1024]^T, then per-head (64-col) RMS norm +
// RoPE + q_gain*0.125 applied on the f32 accumulators for q/k columns.
// Wave covers exactly one 64-col head (wn in {0,64}, n0 multiple of 128).
__global__ __launch_bounds__(256) void gemm_qkv(
    const bf16_t* __restrict__ A, const bf16_t* __restrict__ B,
    bf16_t* __restrict__ C, const float* __restrict__ q_gain, int N, int K) {
  __shared__ bf16_t As[128 * 32];
  __shared__ bf16_t Bs[128 * 32];
  const int tid = threadIdx.x;
  const int lane = tid & 63;
  const int w = tid >> 6;
  const int wm = (w & 1) << 6, wn = (w >> 1) << 6;
  const int m0 = blockIdx.y << 7, n0 = blockIdx.x << 7;
  const int fidx = lane & 15, quad = lane >> 4;
  f32x4 acc[4][4] = {};
  const int c0 = tid, c1 = tid + 256;
  const bf16_t* Ag0 = A + (size_t)(m0 + (c0 >> 2)) * K + (c0 & 3) * 8;
  const bf16_t* Ag1 = A + (size_t)(m0 + (c1 >> 2)) * K + (c1 & 3) * 8;
  const bf16_t* Bg0 = B + (size_t)(n0 + (c0 >> 2)) * K + (c0 & 3) * 8;
  const bf16_t* Bg1 = B + (size_t)(n0 + (c1 >> 2)) * K + (c1 & 3) * 8;
  for (int kt = 0; kt < K; kt += 32) {
    __syncthreads();
    async_load16(Ag0 + kt, As + c0 * 8);
    async_load16(Ag1 + kt, As + c1 * 8);
    async_load16(Bg0 + kt, Bs + c0 * 8);
    async_load16(Bg1 + kt, Bs + c1 * 8);
    __syncthreads();
    bf16x8 af[4], bfr[4];
#pragma unroll
    for (int i = 0; i < 4; i++)
      af[i] = *(const bf16x8*)(As + (wm + i * 16 + fidx) * 32 + quad * 8);
#pragma unroll
    for (int i = 0; i < 4; i++)
      bfr[i] = *(const bf16x8*)(Bs + (wn + i * 16 + fidx) * 32 + quad * 8);
#pragma unroll
    for (int mi = 0; mi < 4; mi++)
#pragma unroll
      for (int ni = 0; ni < 4; ni++)
        acc[mi][ni] = __builtin_amdgcn_mfma_f32_16x16x32_bf16(
            af[mi], bfr[ni], acc[mi][ni], 0, 0, 0);
  }
  // ---- fused epilogue: per-head RMSNorm + RoPE (+ gain for q heads) -------
  const int hc0 = n0 + wn;        // head starting col (multiple of 64)
  const bool is_v = hc0 >= 1280;
  float gain = 1.f;
  if (hc0 < 1024) gain = q_gain[hc0 >> 6] * 0.125f;  // fold softmax scale
  if (!is_v) {
#pragma unroll
    for (int mi = 0; mi < 4; mi++)
#pragma unroll
      for (int r = 0; r < 4; r++) {
        float ss = 0.f;
#pragma unroll
        for (int ni = 0; ni < 4; ni++) { float t = acc[mi][ni][r]; ss += t * t; }
#pragma unroll
        for (int off = 8; off >= 1; off >>= 1) ss += __shfl_xor(ss, off);
        float scl = rsqrtf(ss * (1.f / 64.f) + 1e-6f);
        int s = (m0 + wm + mi * 16 + quad * 4 + r) & (S_LEN - 1);
#pragma unroll
        for (int ni = 0; ni < 2; ni++) {
          float v1 = acc[mi][ni][r] * scl;
          float v2 = acc[mi][ni + 2][r] * scl;
          float fr = (float)(ni * 16 + fidx);
          float ang = (float)s * __expf(fr * -0.28782313662425575f);  // ln(1e4)/32
          float sn, cs;
          __sincosf(ang, &sn, &cs);
          acc[mi][ni][r]     = (v1 * cs + v2 * sn) * gain;
          acc[mi][ni + 2][r] = (-v1 * sn + v2 * cs) * gain;
        }
      }
  }
#pragma unroll
  for (int mi = 0; mi < 4; mi++)
#pragma unroll
    for (int ni = 0; ni < 4; ni++)
#pragma unroll
      for (int r = 0; r < 4; r++) {
        int gr = m0 + wm + mi * 16 + quad * 4 + r;
        int gc = n0 + wn + ni * 16 + fidx;
        C[(size_t)gr * N + gc] = (bf16_t)acc[mi][ni][r];
      }
}

// ---------------- bf16 MFMA GEMM (f32 out): C = A * B^T ---------------------
__global__ __launch_bounds__(256) void gemm_bt_f32(
    const bf16_t* __restrict__ A, const bf16_t* __restrict__ B,
    float* __restrict__ C, int N, int K) {
  __shared__ bf16_t As[128 * 32];
  __shared__ bf16_t Bs[128 * 32];
  const int tid = threadIdx.x;
  const int lane = tid & 63;
  const int w = tid >> 6;
  const int wm = (w & 1) << 6, wn = (w >> 1) << 6;
  const int m0 = blockIdx.y << 7, n0 = blockIdx.x << 7;
  const int fidx = lane & 15, quad = lane >> 4;
  f32x4 acc[4][4] = {};
  const int c0 = tid, c1 = tid + 256;
  const bf16_t* Ag0 = A + (size_t)(m0 + (c0 >> 2)) * K + (c0 & 3) * 8;
  const bf16_t* Ag1 = A + (size_t)(m0 + (c1 >> 2)) * K + (c1 & 3) * 8;
  const bf16_t* Bg0 = B + (size_t)(n0 + (c0 >> 2)) * K + (c0 & 3) * 8;
  const bf16_t* Bg1 = B + (size_t)(n0 + (c1 >> 2)) * K + (c1 & 3) * 8;
  for (int kt = 0; kt < K; kt += 32) {
    __syncthreads();
    async_load16(Ag0 + kt, As + c0 * 8);
    async_load16(Ag1 + kt, As + c1 * 8);
    async_load16(Bg0 + kt, Bs + c0 * 8);
    async_load16(Bg1 + kt, Bs + c1 * 8);
    __syncthreads();
    bf16x8 af[4], bfr[4];
#pragma unroll
    for (int i = 0; i < 4; i++)
      af[i] = *(const bf16x8*)(As + (wm + i * 16 + fidx) * 32 + quad * 8);
#pragma unroll
    for (int i = 0; i < 4; i++)
      bfr[i] = *(const bf16x8*)(Bs + (wn + i * 16 + fidx) * 32 + quad * 8);
#pragma unroll
    for (int mi = 0; mi < 4; mi++)
#pragma unroll
      for (int ni = 0; ni < 4; ni++)
        acc[mi][ni] = __builtin_amdgcn_mfma_f32_16x16x32_bf16(
            af[mi], bfr[ni], acc[mi][ni], 0, 0, 0);
  }
#pragma unroll
  for (int mi = 0; mi < 4; mi++)
#pragma unroll
    for (int ni = 0; ni < 4; ni++)
#pragma unroll
      for (int r = 0; r < 4; r++) {
        int gr = m0 + wm + mi * 16 + quad * 4 + r;
        int gc = n0 + wn + ni * 16 + fidx;
        C[(size_t)gr * N + gc] = acc[mi][ni][r];
      }
}

// ---------------- V transpose: vt[(b*4+g)*64 + d][s] = V[b][s][g][d] --------
__global__ __launch_bounds__(256) void transpose_v(
    const bf16_t* __restrict__ qkv, bf16_t* __restrict__ vt) {
  __shared__ bf16_t tile[64][72];
  const int tid = threadIdx.x;
  const int s0 = blockIdx.x * 64, g = blockIdx.y, b = blockIdx.z;
  const int r = tid >> 2, cg = (tid & 3) * 16;
  const bf16_t* src = qkv + ((size_t)b * S_LEN + s0 + r) * QKV_COLS + 1280 + g * 64 + cg;
  bf16x8 a0 = *(const bf16x8*)src;
  bf16x8 a1 = *(const bf16x8*)(src + 8);
#pragma unroll
  for (int j = 0; j < 8; j++) { tile[r][cg + j] = a0[j]; tile[r][cg + 8 + j] = a1[j]; }
  __syncthreads();
  bf16x8 o0, o1;
#pragma unroll
  for (int j = 0; j < 8; j++) { o0[j] = tile[cg + j][r]; o1[j] = tile[cg + 8 + j][r]; }
  bf16_t* dst = vt + ((size_t)(b * 4 + g) * 64 + r) * S_LEN + s0 + cg;
  *(bf16x8*)dst = o0;
  *(bf16x8*)(dst + 8) = o1;
}

// ---------------- MFMA flash attention + pair mix (32 queries / block) ------
// block = (b, kvh group g, 32-query tile). 4 waves = 4 q heads of the group.
// Each wave: two 16-q M-tiles sharing every K/V chunk fetch.
#define PSTRIDE 40
__global__ __launch_bounds__(256) void attn_mfma(
    const bf16_t* __restrict__ qkv, const bf16_t* __restrict__ vt,
    const float* __restrict__ pair_mix, bf16_t* __restrict__ yb) {
  __shared__ bf16_t plds[4][16 * PSTRIDE];
  __shared__ float olds[4][32][64];
  const int tid = threadIdx.x, lane = tid & 63, w = tid >> 6;
  const int col = lane & 15, quad = lane >> 4;
  const int q0 = blockIdx.x * 32, g = blockIdx.y, b = blockIdx.z;
  const int h = g * 4 + w;

  bf16x8 qf[2][2];
#pragma unroll
  for (int t = 0; t < 2; t++) {
    const bf16_t* qb =
        qkv + ((size_t)b * S_LEN + q0 + t * 16 + col) * QKV_COLS + h * 64 + quad * 8;
    qf[t][0] = *(const bf16x8*)qb;
    qf[t][1] = *(const bf16x8*)(qb + 32);
  }
  const bf16_t* kbase = qkv + (size_t)b * S_LEN * QKV_COLS + 1024 + g * 64 + quad * 8;
  const bf16_t* vbase = vt + ((size_t)(b * 4 + g) * 64 + col) * S_LEN + quad * 8;

  f32x4 o[2][4] = {};
  float m[2][4], l[2][4];
#pragma unroll
  for (int t = 0; t < 2; t++)
#pragma unroll
    for (int r = 0; r < 4; r++) { m[t][r] = -1e30f; l[t][r] = 0.f; }

  const int c_lo = max(0, (q0 - 255) >> 5);
  const int c_hi = (q0 + 31) >> 5;
  for (int c = c_lo; c <= c_hi; c++) {
    const int k0 = c * 32;
    bf16x8 kf[2][2];
#pragma unroll
    for (int nt = 0; nt < 2; nt++) {
      const bf16_t* kp = kbase + (size_t)(k0 + nt * 16 + col) * QKV_COLS;
      kf[nt][0] = *(const bf16x8*)kp;
      kf[nt][1] = *(const bf16x8*)(kp + 32);
    }
    bf16x8 vf[4];
#pragma unroll
    for (int nt2 = 0; nt2 < 4; nt2++)
      vf[nt2] = *(const bf16x8*)(vbase + (size_t)(nt2 * 16) * S_LEN + k0);

#pragma unroll
    for (int t = 0; t < 2; t++) {
      f32x4 s[2];
#pragma unroll
      for (int nt = 0; nt < 2; nt++) {
        f32x4 a = {};
        a = __builtin_amdgcn_mfma_f32_16x16x32_bf16(qf[t][0], kf[nt][0], a, 0, 0, 0);
        a = __builtin_amdgcn_mfma_f32_16x16x32_bf16(qf[t][1], kf[nt][1], a, 0, 0, 0);
        s[nt] = a;
      }
      float alpha[4];
#pragma unroll
      for (int r = 0; r < 4; r++) {
        int q = q0 + t * 16 + quad * 4 + r;
#pragma unroll
        for (int nt = 0; nt < 2; nt++) {
          int k = k0 + nt * 16 + col;
          bool valid = (k <= q) && (q - k < 256);
          s[nt][r] = valid ? s[nt][r] : -1e30f;
        }
        float v = fmaxf(s[0][r], s[1][r]);
#pragma unroll
        for (int off = 8; off >= 1; off >>= 1) v = fmaxf(v, __shfl_xor(v, off));
        float mn = fmaxf(m[t][r], v);
        alpha[r] = __expf(m[t][r] - mn);
        m[t][r] = mn;
      }
      float psum[4] = {0.f, 0.f, 0.f, 0.f};
#pragma unroll
      for (int nt = 0; nt < 2; nt++) {
#pragma unroll
        for (int r = 0; r < 4; r++) {
          float sv = s[nt][r];
          float p = (sv > -1e29f) ? __expf(sv - m[t][r]) : 0.f;
          psum[r] += p;
          plds[w][(quad * 4 + r) * PSTRIDE + nt * 16 + col] = (bf16_t)p;
        }
      }
#pragma unroll
      for (int r = 0; r < 4; r++) {
        float v = psum[r];
#pragma unroll
        for (int off = 8; off >= 1; off >>= 1) v += __shfl_xor(v, off);
        l[t][r] = l[t][r] * alpha[r] + v;
#pragma unroll
        for (int nt2 = 0; nt2 < 4; nt2++) o[t][nt2][r] *= alpha[r];
      }
      asm volatile("s_waitcnt lgkmcnt(0)" ::: "memory");
      bf16x8 pf = *(const bf16x8*)(plds[w] + col * PSTRIDE + quad * 8);
#pragma unroll
      for (int nt2 = 0; nt2 < 4; nt2++)
        o[t][nt2] = __builtin_amdgcn_mfma_f32_16x16x32_bf16(pf, vf[nt2], o[t][nt2], 0, 0, 0);
    }
  }
#pragma unroll
  for (int t = 0; t < 2; t++)
#pragma unroll
    for (int r = 0; r < 4; r++) {
      float il = 1.f / l[t][r];
#pragma unroll
      for (int nt2 = 0; nt2 < 4; nt2++)
        olds[w][t * 16 + quad * 4 + r][nt2 * 16 + col] = o[t][nt2][r] * il;
    }
  __syncthreads();
  // pair mix + coalesced bf16x8 writes (8192 outputs / block)
#pragma unroll
  for (int i = 0; i < 4; i++) {
    int chunk = i * 256 + tid;    // 0..1023
    int tok = chunk >> 5;         // 0..31
    int cg = chunk & 31;
    int hh = cg >> 3;
    int d0 = (cg & 7) * 8;
    int p_loc = hh >> 1, oo = hh & 1;
    int wb = p_loc * 2;
    int hp = g * 2 + p_loc;
    float pm0 = pair_mix[hp * 4 + oo * 2 + 0];
    float pm1 = pair_mix[hp * 4 + oo * 2 + 1];
    bf16x8 outv;
#pragma unroll
    for (int j = 0; j < 8; j++)
      outv[j] = (bf16_t)(pm0 * olds[wb][tok][d0 + j] + pm1 * olds[wb + 1][tok][d0 + j]);
    *(bf16x8*)(yb + ((size_t)b * S_LEN + q0 + tok) * 1024 + (g * 4 + hh) * 64 + d0) = outv;
  }
}

extern "C" void kernel_launch(void* const* d_in, const int* in_sizes, int n_in,
                              void* d_out, int out_size, void* d_ws, size_t ws_size,
                              hipStream_t stream) {
  const float* x        = (const float*)d_in[0];
  const float* Wq       = (const float*)d_in[1];
  const float* Wk       = (const float*)d_in[2];
  const float* Wv       = (const float*)d_in[3];
  const float* Wo       = (const float*)d_in[4];
  const float* q_gain   = (const float*)d_in[5];
  const float* pair_mix = (const float*)d_in[6];
  float* out = (float*)d_out;

  bf16_t* ws    = (bf16_t*)d_ws;
  bf16_t* xb    = ws;                   // 4096*1024 (dead after gemm_qkv; vt aliases it)
  bf16_t* wqkvb = xb + 4096 * 1024;     // 1536*1024
  bf16_t* wob   = wqkvb + 1536 * 1024;  // 1024*1024
  bf16_t* qkvb  = wob + 1024 * 1024;    // 4096*1536
  bf16_t* yb    = qkvb + 4096 * 1536;   // 4096*1024  (total ~34.6 MB)
  bf16_t* vt    = xb;                   // 8*64*2048 = 1M bf16, aliases xb

  convert_all<<<6656, 256, 0, stream>>>(
      (const float4*)x, (const float4*)Wq, (const float4*)Wk, (const float4*)Wv,
      (const float4*)Wo, (bf16x4*)xb, (bf16x4*)wqkvb, (bf16x4*)wob);
  gemm_qkv<<<dim3(12, 32), 256, 0, stream>>>(xb, wqkvb, qkvb, q_gain, 1536, 1024);
  transpose_v<<<dim3(32, 4, 2), 256, 0, stream>>>(qkvb, vt);
  attn_mfma<<<dim3(64, 4, 2), 256, 0, stream>>>(qkvb, vt, pair_mix, yb);
  gemm_bt_f32<<<dim3(8, 32), 256, 0, stream>>>(yb, wob, out, 1024, 1024);
}